// Round 1
// baseline (3765.166 us; speedup 1.0000x reference)
//
#include <hip/hip_runtime.h>
#include <hip/hip_bf16.h>

// Sizes (fixed by the reference, but N/E derived from in_sizes at launch):
// N=50000, E=400000, D=128, DE=64, H=8
#define D 128
#define DE 64
#define NH 8
#define SLOPE 0.2f
#define EPS 1e-5f

__device__ __forceinline__ float lrelu(float x) { return x > 0.f ? x : SLOPE * x; }

// ---------------------------------------------------------------------------
// K0: fold weights.  Afold[320][128], bfold[128]
//   rows 0..127   : Wq @ A1[0:128]
//   rows 128..255 : Wk @ A1[128:256]
//   rows 256..319 : We @ A1[256:384]
//   bfold = b1 + bq@A1q + bk@A1k + be@A1e
// grid 321 x 128 threads (block 320 computes bias)
__global__ __launch_bounds__(128) void fold_kernel(
    const float* __restrict__ Wq, const float* __restrict__ Wk,
    const float* __restrict__ We, const float* __restrict__ A1,
    const float* __restrict__ bq, const float* __restrict__ bk,
    const float* __restrict__ be, const float* __restrict__ b1,
    float* __restrict__ Afold, float* __restrict__ bfold) {
  int r = blockIdx.x;
  int j = threadIdx.x;
  if (r < 128) {
    float acc = 0.f;
    for (int t = 0; t < 128; ++t) acc += Wq[r * 128 + t] * A1[t * 128 + j];
    Afold[r * 128 + j] = acc;
  } else if (r < 256) {
    int i = r - 128;
    float acc = 0.f;
    for (int t = 0; t < 128; ++t) acc += Wk[i * 128 + t] * A1[(128 + t) * 128 + j];
    Afold[r * 128 + j] = acc;
  } else if (r < 320) {
    int i = r - 256;
    float acc = 0.f;
    for (int t = 0; t < 128; ++t) acc += We[i * 128 + t] * A1[(256 + t) * 128 + j];
    Afold[r * 128 + j] = acc;
  } else {
    float acc = b1[j];
    for (int t = 0; t < 128; ++t) {
      acc += bq[t] * A1[t * 128 + j];
      acc += bk[t] * A1[(128 + t) * 128 + j];
      acc += be[t] * A1[(256 + t) * 128 + j];
    }
    bfold[j] = acc;
  }
}

// ---------------------------------------------------------------------------
// K1: node GEMMs.  blockIdx.y==0 -> h = X@Wn+bn (into d_out), ==1 -> v = X@Wv+bv
// Tile: 32 nodes x 128 cols, 256 threads, 16 acc/thread, K-chunks of 64.
__global__ __launch_bounds__(256) void node_gemm(
    const float* __restrict__ X, const float* __restrict__ Wn,
    const float* __restrict__ bn, const float* __restrict__ Wv,
    const float* __restrict__ bv, float* __restrict__ h, float* __restrict__ v,
    int N) {
  __shared__ float As[32][65];
  __shared__ float Bs[64][128];
  const float* W;
  const float* b;
  float* O;
  if (blockIdx.y == 0) { W = Wn; b = bn; O = h; }
  else                 { W = Wv; b = bv; O = v; }
  int tid = threadIdx.x;
  int er = tid >> 3, cg = tid & 7;
  int m0 = blockIdx.x * 32;
  float acc[16];
#pragma unroll
  for (int j = 0; j < 16; ++j) acc[j] = 0.f;
  for (int kc = 0; kc < 128; kc += 64) {
#pragma unroll
    for (int l = 0; l < 8; ++l) {
      int idx = tid + l * 256;
      int r = idx >> 6, c = idx & 63;
      int row = m0 + r;
      As[r][c] = (row < N) ? X[(size_t)row * D + kc + c] : 0.f;
    }
#pragma unroll
    for (int l = 0; l < 32; ++l) {
      int idx = tid + l * 256;
      int r = idx >> 7, c = idx & 127;
      Bs[r][c] = W[(kc + r) * 128 + c];
    }
    __syncthreads();
#pragma unroll
    for (int kk = 0; kk < 64; ++kk) {
      float a = As[er][kk];
#pragma unroll
      for (int j = 0; j < 16; ++j) acc[j] += a * Bs[kk][cg + 8 * j];
    }
    __syncthreads();
  }
  int row = m0 + er;
  if (row < N) {
#pragma unroll
    for (int j = 0; j < 16; ++j) {
      int c = cg + 8 * j;
      O[(size_t)row * D + c] = acc[j] + b[c];
    }
  }
}

// ---------------------------------------------------------------------------
// K2: edge pipeline.  s[e] = mean_h lrelu( lrelu(attn@Afold + bfold) @ A2 + b2 )
// where attn rows are gathered [X[src], X[tgt], EF[e]] (K=320).
// Tile: 32 edges x 128 cols, 256 threads, 5 K-chunks of 64.  E % 32 == 0.
__global__ __launch_bounds__(256) void edge_gemm(
    const float* __restrict__ X, const float* __restrict__ EF,
    const float* __restrict__ Afold, const float* __restrict__ bfold,
    const float* __restrict__ A2, const float* __restrict__ b2,
    const int* __restrict__ src, const int* __restrict__ tgt,
    float* __restrict__ s_out) {
  __shared__ float As[32][65];
  __shared__ float Bs[64][128];  // also reused as Hs[32][129] in the epilogue
  __shared__ float A2s[128 * 8];
  __shared__ float b2s[8];
  __shared__ int sIdx[64];  // [0:32)=src, [32:64)=tgt
  int tid = threadIdx.x;
  int e0 = blockIdx.x * 32;
  if (tid < 32) sIdx[tid] = src[e0 + tid];
  else if (tid < 64) sIdx[tid] = tgt[e0 + tid - 32];
#pragma unroll
  for (int l = 0; l < 4; ++l) A2s[tid + l * 256] = A2[tid + l * 256];
  if (tid < 8) b2s[tid] = b2[tid];
  __syncthreads();

  int er = tid >> 3, cg = tid & 7;
  float acc[16];
#pragma unroll
  for (int j = 0; j < 16; ++j) acc[j] = 0.f;

  for (int ch = 0; ch < 5; ++ch) {
#pragma unroll
    for (int l = 0; l < 8; ++l) {
      int idx = tid + l * 256;
      int r = idx >> 6, c = idx & 63;
      float val;
      if (ch < 2)      val = X[(size_t)sIdx[r] * D + ch * 64 + c];
      else if (ch < 4) val = X[(size_t)sIdx[32 + r] * D + (ch - 2) * 64 + c];
      else             val = EF[(size_t)(e0 + r) * DE + c];
      As[r][c] = val;
    }
#pragma unroll
    for (int l = 0; l < 32; ++l) {
      int idx = tid + l * 256;
      int r = idx >> 7, c = idx & 127;
      Bs[r][c] = Afold[(ch * 64 + r) * 128 + c];
    }
    __syncthreads();
#pragma unroll
    for (int kk = 0; kk < 64; ++kk) {
      float a = As[er][kk];
#pragma unroll
      for (int j = 0; j < 16; ++j) acc[j] += a * Bs[kk][cg + 8 * j];
    }
    __syncthreads();
  }

  // epilogue: bias + lrelu -> Hs (aliased over Bs), then 128x8 head stage
  float* Hs = &Bs[0][0];
#pragma unroll
  for (int j = 0; j < 16; ++j) {
    int c = cg + 8 * j;
    Hs[er * 129 + c] = lrelu(acc[j] + bfold[c]);
  }
  __syncthreads();
  int hh = tid & 7;
  float dot = b2s[hh];
#pragma unroll
  for (int j = 0; j < 128; ++j) dot += Hs[er * 129 + j] * A2s[j * 8 + hh];
  dot = lrelu(dot);
  dot += __shfl_xor(dot, 1);
  dot += __shfl_xor(dot, 2);
  dot += __shfl_xor(dot, 4);
  if (hh == 0) s_out[e0 + er] = dot * 0.125f;
}

// ---------------------------------------------------------------------------
// K3: per-block online (max, sum-exp) partials over s[E]
__global__ __launch_bounds__(256) void softmax_partial(
    const float* __restrict__ s, int E, float2* __restrict__ part) {
  __shared__ float mS[256], sS[256];
  int tid = threadIdx.x;
  float m = -1e30f, sum = 0.f;
  for (int i = blockIdx.x * 256 + tid; i < E; i += gridDim.x * 256) {
    float x = s[i];
    if (x > m) {
      sum = sum * __expf(m - x) + 1.f;
      m = x;
    } else {
      sum += __expf(x - m);
    }
  }
  mS[tid] = m;
  sS[tid] = sum;
  __syncthreads();
  for (int off = 128; off > 0; off >>= 1) {
    if (tid < off) {
      float m1 = mS[tid], s1 = sS[tid];
      float m2 = mS[tid + off], s2 = sS[tid + off];
      float M = fmaxf(m1, m2);
      mS[tid] = M;
      sS[tid] = s1 * __expf(m1 - M) + s2 * __expf(m2 - M);
    }
    __syncthreads();
  }
  if (tid == 0) part[blockIdx.x] = make_float2(mS[0], sS[0]);
}

// K4: final reduce of 1024 partials -> MS[0]=M, MS[1]=1/sum
__global__ __launch_bounds__(256) void softmax_final(
    const float2* __restrict__ part, int nPart, float* __restrict__ MS) {
  __shared__ float mS[256], sS[256];
  int tid = threadIdx.x;
  float m = -1e30f, sum = 0.f;
  for (int i = tid; i < nPart; i += 256) {
    float2 p = part[i];
    float M = fmaxf(m, p.x);
    sum = sum * __expf(m - M) + p.y * __expf(p.x - M);
    m = M;
  }
  mS[tid] = m;
  sS[tid] = sum;
  __syncthreads();
  for (int off = 128; off > 0; off >>= 1) {
    if (tid < off) {
      float m1 = mS[tid], s1 = sS[tid];
      float m2 = mS[tid + off], s2 = sS[tid + off];
      float M = fmaxf(m1, m2);
      mS[tid] = M;
      sS[tid] = s1 * __expf(m1 - M) + s2 * __expf(m2 - M);
    }
    __syncthreads();
  }
  if (tid == 0) {
    MS[0] = mS[0];
    MS[1] = 1.f / sS[0];
  }
}

// ---------------------------------------------------------------------------
// K5: scatter  out[src[e]] += w_e * v[tgt[e]]    (2 edges per 256-block)
__global__ __launch_bounds__(256) void scatter_edges(
    const float* __restrict__ s, const float* __restrict__ MS,
    const int* __restrict__ src, const int* __restrict__ tgt,
    const float* __restrict__ v, float* __restrict__ out) {
  int tid = threadIdx.x;
  int e = blockIdx.x * 2 + (tid >> 7);
  int d = tid & 127;
  float w = __expf(s[e] - MS[0]) * MS[1];
  int si = src[e], ti = tgt[e];
  atomicAdd(&out[(size_t)si * D + d], w * v[(size_t)ti * D + d]);
}

// ---------------------------------------------------------------------------
// K6: y = LayerNorm(h + out) * gamma + beta.   One wave per node (2 elems/lane).
// h lives in d_out; written back in place (each thread reads its own elements
// before writing them).
__global__ __launch_bounds__(256) void layernorm_kernel(
    const float* __restrict__ out_acc, const float* __restrict__ gamma,
    const float* __restrict__ beta, float* __restrict__ y, int N) {
  int tid = threadIdx.x;
  int n = blockIdx.x * 4 + (tid >> 6);
  if (n >= N) return;
  int lane = tid & 63;
  size_t base = (size_t)n * D;
  float y0 = y[base + lane] + out_acc[base + lane];
  float y1 = y[base + 64 + lane] + out_acc[base + 64 + lane];
  float sum = y0 + y1;
  float ssq = y0 * y0 + y1 * y1;
#pragma unroll
  for (int off = 1; off < 64; off <<= 1) {
    sum += __shfl_xor(sum, off);
    ssq += __shfl_xor(ssq, off);
  }
  float mu = sum * (1.f / 128.f);
  float var = ssq * (1.f / 128.f) - mu * mu;
  float rstd = rsqrtf(var + EPS);
  y[base + lane] = gamma[lane] * (y0 - mu) * rstd + beta[lane];
  y[base + 64 + lane] = gamma[64 + lane] * (y1 - mu) * rstd + beta[64 + lane];
}

// ---------------------------------------------------------------------------
extern "C" void kernel_launch(void* const* d_in, const int* in_sizes, int n_in,
                              void* d_out, int out_size, void* d_ws,
                              size_t ws_size, hipStream_t stream) {
  const float* X  = (const float*)d_in[0];
  const float* EF = (const float*)d_in[1];
  const float* Wn = (const float*)d_in[2];
  const float* bn = (const float*)d_in[3];
  const float* Wq = (const float*)d_in[4];
  const float* bq = (const float*)d_in[5];
  const float* Wk = (const float*)d_in[6];
  const float* bk = (const float*)d_in[7];
  const float* Wv = (const float*)d_in[8];
  const float* bv = (const float*)d_in[9];
  const float* We = (const float*)d_in[10];
  const float* be = (const float*)d_in[11];
  const float* A1 = (const float*)d_in[12];
  const float* b1 = (const float*)d_in[13];
  const float* A2 = (const float*)d_in[14];
  const float* b2 = (const float*)d_in[15];
  const float* gamma = (const float*)d_in[16];
  const float* beta  = (const float*)d_in[17];
  const int* ei = (const int*)d_in[18];

  int N = in_sizes[0] / D;   // 50000
  int E = in_sizes[1] / DE;  // 400000
  const int* src = ei;
  const int* tgt = ei + E;

  float* h = (float*)d_out;  // h lives in d_out (layernorm finalizes in place)
  float* ws = (float*)d_ws;
  float* v     = ws;
  float* outa  = v + (size_t)N * D;
  float* Afold = outa + (size_t)N * D;
  float* bfold = Afold + 320 * 128;
  float* sbuf  = bfold + 128;
  float2* part = (float2*)(sbuf + E);
  float* MS    = (float*)(part + 1024);

  hipMemsetAsync(outa, 0, (size_t)N * D * sizeof(float), stream);
  fold_kernel<<<321, 128, 0, stream>>>(Wq, Wk, We, A1, bq, bk, be, b1, Afold,
                                       bfold);
  node_gemm<<<dim3((N + 31) / 32, 2), 256, 0, stream>>>(X, Wn, bn, Wv, bv, h,
                                                        v, N);
  edge_gemm<<<E / 32, 256, 0, stream>>>(X, EF, Afold, bfold, A2, b2, src, tgt,
                                        sbuf);
  softmax_partial<<<1024, 256, 0, stream>>>(sbuf, E, part);
  softmax_final<<<1, 256, 0, stream>>>(part, 1024, MS);
  scatter_edges<<<E / 2, 256, 0, stream>>>(sbuf, MS, src, tgt, v, outa);
  layernorm_kernel<<<(N + 3) / 4, 256, 0, stream>>>(outa, gamma, beta, h, N);
}

// Round 2
// 548.758 us; speedup vs baseline: 6.8613x; 6.8613x over previous
//
#include <hip/hip_runtime.h>

// N=50000, E=400000, D=128, DE=64, H=8
#define D 128
#define DE 64
#define SLOPE 0.2f
#define EPS 1e-5f

typedef float f32x4 __attribute__((ext_vector_type(4)));
typedef short bf16x8 __attribute__((ext_vector_type(8)));

__device__ __forceinline__ float lrelu(float x) { return x > 0.f ? x : SLOPE * x; }

// fp32 -> bf16 RNE
__device__ __forceinline__ unsigned short f2bf(float x) {
  union { float f; unsigned u; } c; c.f = x;
  unsigned r = c.u + 0x7FFFu + ((c.u >> 16) & 1u);
  return (unsigned short)(r >> 16);
}

// ---------------------------------------------------------------------------
// K0: fold weights (fp32).  Afold[320][128], bfold[128]
__global__ __launch_bounds__(128) void fold_kernel(
    const float* __restrict__ Wq, const float* __restrict__ Wk,
    const float* __restrict__ We, const float* __restrict__ A1,
    const float* __restrict__ bq, const float* __restrict__ bk,
    const float* __restrict__ be, const float* __restrict__ b1,
    float* __restrict__ Afold, float* __restrict__ bfold) {
  int r = blockIdx.x;
  int j = threadIdx.x;
  if (r < 128) {
    float acc = 0.f;
    for (int t = 0; t < 128; ++t) acc += Wq[r * 128 + t] * A1[t * 128 + j];
    Afold[r * 128 + j] = acc;
  } else if (r < 256) {
    int i = r - 128;
    float acc = 0.f;
    for (int t = 0; t < 128; ++t) acc += Wk[i * 128 + t] * A1[(128 + t) * 128 + j];
    Afold[r * 128 + j] = acc;
  } else if (r < 320) {
    int i = r - 256;
    float acc = 0.f;
    for (int t = 0; t < 128; ++t) acc += We[i * 128 + t] * A1[(256 + t) * 128 + j];
    Afold[r * 128 + j] = acc;
  } else {
    float acc = b1[j];
    for (int t = 0; t < 128; ++t) {
      acc += bq[t] * A1[t * 128 + j];
      acc += bk[t] * A1[(128 + t) * 128 + j];
      acc += be[t] * A1[(256 + t) * 128 + j];
    }
    bfold[j] = acc;
  }
}

// ---------------------------------------------------------------------------
// Pack Afold -> AfT (bf16, [col][k], col-major k-contiguous), Wn/Wv -> WT bf16
__global__ __launch_bounds__(256) void pack_weights(
    const float* __restrict__ Afold, const float* __restrict__ Wn,
    const float* __restrict__ Wv, unsigned short* __restrict__ AfT,
    unsigned short* __restrict__ WnT, unsigned short* __restrict__ WvT) {
  int i = blockIdx.x * 256 + threadIdx.x;
  if (i < 128 * 320) {
    int c = i / 320, k = i - c * 320;
    AfT[i] = f2bf(Afold[k * 128 + c]);
  }
  if (i < 128 * 128) {
    int c = i >> 7, k = i & 127;
    WnT[i] = f2bf(Wn[k * 128 + c]);
    WvT[i] = f2bf(Wv[k * 128 + c]);
  }
}

// X fp32 -> bf16 (row-major unchanged)
__global__ __launch_bounds__(256) void cvt_to_bf16(
    const float* __restrict__ X, unsigned short* __restrict__ Xb, int n4) {
  int i = blockIdx.x * 256 + threadIdx.x;
  if (i < n4) {
    float4 f = ((const float4*)X)[i];
    union { unsigned short us[4]; uint2 v; } u;
    u.us[0] = f2bf(f.x); u.us[1] = f2bf(f.y);
    u.us[2] = f2bf(f.z); u.us[3] = f2bf(f.w);
    ((uint2*)Xb)[i] = u.v;
  }
}

// ---------------------------------------------------------------------------
// K1: node GEMMs via MFMA.  y==0 -> h = X@Wn+bn, y==1 -> v = X@Wv+bv
// Block: 256 threads = 4 waves, tile 256 rows x 128 cols, K=128 (4 chunks).
__global__ __launch_bounds__(256, 2) void node_gemm_mfma(
    const unsigned short* __restrict__ Xb, const unsigned short* __restrict__ WnT,
    const unsigned short* __restrict__ WvT, const float* __restrict__ bn,
    const float* __restrict__ bv, float* __restrict__ h, float* __restrict__ v,
    int Nn) {
  __shared__ unsigned short As[256 * 40];  // stride 40 bf16 (+8 pad)
  __shared__ unsigned short Bs[128 * 40];
  __shared__ float bS[128];
  const unsigned short* WT;
  const float* bb;
  float* O;
  if (blockIdx.y == 0) { WT = WnT; bb = bn; O = h; }
  else                 { WT = WvT; bb = bv; O = v; }
  const int t = threadIdx.x;
  if (t < 128) bS[t] = bb[t];
  const int seg = t & 3, arow = t >> 2;
  const int m0 = blockIdx.x * 256;
  int rIdx[4];
#pragma unroll
  for (int l = 0; l < 4; ++l) rIdx[l] = min(m0 + arow + 64 * l, Nn - 1);
  uint4 avA[4], avB[2];
#pragma unroll
  for (int l = 0; l < 4; ++l)
    avA[l] = *(const uint4*)(Xb + (size_t)rIdx[l] * 128 + seg * 8);
#pragma unroll
  for (int l = 0; l < 2; ++l)
    avB[l] = *(const uint4*)(WT + (arow + 64 * l) * 128 + seg * 8);
  f32x4 acc[4][8];
#pragma unroll
  for (int mt = 0; mt < 4; ++mt)
#pragma unroll
    for (int nt = 0; nt < 8; ++nt) acc[mt][nt] = (f32x4)(0.f);
  const int lane = t & 63, wv = t >> 6, l15 = lane & 15, quad = lane >> 4;
  for (int ch = 0; ch < 4; ++ch) {
#pragma unroll
    for (int l = 0; l < 4; ++l)
      *(uint4*)&As[(arow + 64 * l) * 40 + seg * 8] = avA[l];
#pragma unroll
    for (int l = 0; l < 2; ++l)
      *(uint4*)&Bs[(arow + 64 * l) * 40 + seg * 8] = avB[l];
    __syncthreads();
    if (ch < 3) {
      int o = (ch + 1) * 32 + seg * 8;
#pragma unroll
      for (int l = 0; l < 4; ++l)
        avA[l] = *(const uint4*)(Xb + (size_t)rIdx[l] * 128 + o);
#pragma unroll
      for (int l = 0; l < 2; ++l)
        avB[l] = *(const uint4*)(WT + (arow + 64 * l) * 128 + o);
    }
    bf16x8 af[4];
#pragma unroll
    for (int mt = 0; mt < 4; ++mt)
      af[mt] = *(const bf16x8*)&As[(wv * 64 + mt * 16 + l15) * 40 + quad * 8];
#pragma unroll
    for (int nt = 0; nt < 8; ++nt) {
      bf16x8 bfr = *(const bf16x8*)&Bs[(nt * 16 + l15) * 40 + quad * 8];
#pragma unroll
      for (int mt = 0; mt < 4; ++mt)
        acc[mt][nt] =
            __builtin_amdgcn_mfma_f32_16x16x32_bf16(af[mt], bfr, acc[mt][nt], 0, 0, 0);
    }
    __syncthreads();
  }
  // epilogue: + bias, fp32 store.  D layout: col=lane&15, row=quad*4+reg.
#pragma unroll
  for (int mt = 0; mt < 4; ++mt) {
    int rowb = m0 + wv * 64 + mt * 16 + quad * 4;
#pragma unroll
    for (int nt = 0; nt < 8; ++nt) {
      int col = nt * 16 + l15;
      float b = bS[col];
#pragma unroll
      for (int r = 0; r < 4; ++r) {
        int rg = rowb + r;
        if (rg < Nn) O[(size_t)rg * 128 + col] = acc[mt][nt][r] + b;
      }
    }
  }
}

// ---------------------------------------------------------------------------
// K2: fused edge pipeline via MFMA.
//  hmid = lrelu([X[src],X[tgt],EF] @ Afold + bfold)   (MFMA, K=320)
//  s[e] = mean_h lrelu(hmid @ A2 + b2)                (VALU epilogue)
// Block: 256 threads = 4 waves, tile 256 edges x 128 cols.
__global__ __launch_bounds__(256, 2) void edge_fused_mfma(
    const unsigned short* __restrict__ Xb, const float* __restrict__ EF,
    const unsigned short* __restrict__ AfT, const float* __restrict__ bfold,
    const float* __restrict__ A2, const float* __restrict__ b2,
    const int* __restrict__ src, const int* __restrict__ tgt,
    float* __restrict__ s_out, int E) {
  __shared__ unsigned short As[256 * 40];
  __shared__ unsigned short Bs[128 * 40];
  __shared__ float A2s[128 * 9];  // stride 9: conflict-free epilogue reads
  __shared__ float bfS[128];
  __shared__ float b2s[8];
  __shared__ int sIdxS[256], sIdxT[256];
  const int t = threadIdx.x;
  const int e0 = blockIdx.x * 256;
  {
    int ec = min(e0 + t, E - 1);
    sIdxS[t] = src[ec];
    sIdxT[t] = tgt[ec];
    if (t < 128) bfS[t] = bfold[t];
    if (t < 8) b2s[t] = b2[t];
#pragma unroll
    for (int l = 0; l < 4; ++l) {
      int i = t + l * 256;  // 0..1023 over [128][8]
      A2s[(i >> 3) * 9 + (i & 7)] = A2[i];
    }
  }
  __syncthreads();
  const int seg = t & 3, arow = t >> 2;
  int si[4], ti[4], ecl[4];
#pragma unroll
  for (int l = 0; l < 4; ++l) {
    si[l] = sIdxS[arow + 64 * l];
    ti[l] = sIdxT[arow + 64 * l];
    ecl[l] = min(e0 + arow + 64 * l, E - 1);
  }
  uint4 avA[4], avB[2];
#pragma unroll
  for (int l = 0; l < 4; ++l)
    avA[l] = *(const uint4*)(Xb + (size_t)si[l] * 128 + seg * 8);
#pragma unroll
  for (int l = 0; l < 2; ++l)
    avB[l] = *(const uint4*)(AfT + (arow + 64 * l) * 320 + seg * 8);
  f32x4 acc[4][8];
#pragma unroll
  for (int mt = 0; mt < 4; ++mt)
#pragma unroll
    for (int nt = 0; nt < 8; ++nt) acc[mt][nt] = (f32x4)(0.f);
  const int lane = t & 63, wv = t >> 6, l15 = lane & 15, quad = lane >> 4;

  for (int ch = 0; ch < 10; ++ch) {
#pragma unroll
    for (int l = 0; l < 4; ++l)
      *(uint4*)&As[(arow + 64 * l) * 40 + seg * 8] = avA[l];
#pragma unroll
    for (int l = 0; l < 2; ++l)
      *(uint4*)&Bs[(arow + 64 * l) * 40 + seg * 8] = avB[l];
    __syncthreads();
    if (ch < 9) {
      int cn = ch + 1;
      if (cn < 4) {
        int o = cn * 32 + seg * 8;
#pragma unroll
        for (int l = 0; l < 4; ++l)
          avA[l] = *(const uint4*)(Xb + (size_t)si[l] * 128 + o);
      } else if (cn < 8) {
        int o = (cn - 4) * 32 + seg * 8;
#pragma unroll
        for (int l = 0; l < 4; ++l)
          avA[l] = *(const uint4*)(Xb + (size_t)ti[l] * 128 + o);
      } else {
        int o = (cn - 8) * 32 + seg * 8;
#pragma unroll
        for (int l = 0; l < 4; ++l) {
          const float* p = EF + (size_t)ecl[l] * 64 + o;
          float4 f0 = *(const float4*)p;
          float4 f1 = *(const float4*)(p + 4);
          union { unsigned short us[8]; uint4 v; } u;
          u.us[0] = f2bf(f0.x); u.us[1] = f2bf(f0.y);
          u.us[2] = f2bf(f0.z); u.us[3] = f2bf(f0.w);
          u.us[4] = f2bf(f1.x); u.us[5] = f2bf(f1.y);
          u.us[6] = f2bf(f1.z); u.us[7] = f2bf(f1.w);
          avA[l] = u.v;
        }
      }
      int ob = cn * 32 + seg * 8;
#pragma unroll
      for (int l = 0; l < 2; ++l)
        avB[l] = *(const uint4*)(AfT + (arow + 64 * l) * 320 + ob);
    }
    bf16x8 af[4];
#pragma unroll
    for (int mt = 0; mt < 4; ++mt)
      af[mt] = *(const bf16x8*)&As[(wv * 64 + mt * 16 + l15) * 40 + quad * 8];
#pragma unroll
    for (int nt = 0; nt < 8; ++nt) {
      bf16x8 bfr = *(const bf16x8*)&Bs[(nt * 16 + l15) * 40 + quad * 8];
#pragma unroll
      for (int mt = 0; mt < 4; ++mt)
        acc[mt][nt] =
            __builtin_amdgcn_mfma_f32_16x16x32_bf16(af[mt], bfr, acc[mt][nt], 0, 0, 0);
    }
    __syncthreads();
  }

  // epilogue: bias + lrelu in place, then 128x8 head stage + mean.
  float bfv[8];
#pragma unroll
  for (int nt = 0; nt < 8; ++nt) bfv[nt] = bfS[nt * 16 + l15];
#pragma unroll
  for (int mt = 0; mt < 4; ++mt)
#pragma unroll
    for (int nt = 0; nt < 8; ++nt)
#pragma unroll
      for (int r = 0; r < 4; ++r)
        acc[mt][nt][r] = lrelu(acc[mt][nt][r] + bfv[nt]);
  float tacc[4][4];
#pragma unroll
  for (int mt = 0; mt < 4; ++mt)
#pragma unroll
    for (int r = 0; r < 4; ++r) tacc[mt][r] = 0.f;
  for (int hh = 0; hh < 8; ++hh) {
    float a2v[8];
#pragma unroll
    for (int nt = 0; nt < 8; ++nt) a2v[nt] = A2s[nt * 144 + l15 * 9 + hh];
    float b2h = b2s[hh];
#pragma unroll
    for (int mt = 0; mt < 4; ++mt)
#pragma unroll
      for (int r = 0; r < 4; ++r) {
        float p = 0.f;
#pragma unroll
        for (int nt = 0; nt < 8; ++nt) p += acc[mt][nt][r] * a2v[nt];
        p += __shfl_xor(p, 1);
        p += __shfl_xor(p, 2);
        p += __shfl_xor(p, 4);
        p += __shfl_xor(p, 8);
        tacc[mt][r] += lrelu(p + b2h);
      }
  }
  if (l15 == 0) {
#pragma unroll
    for (int mt = 0; mt < 4; ++mt)
#pragma unroll
      for (int r = 0; r < 4; ++r) {
        int e = e0 + wv * 64 + mt * 16 + quad * 4 + r;
        if (e < E) s_out[e] = tacc[mt][r] * 0.125f;
      }
  }
}

// ---------------------------------------------------------------------------
// K3: per-block online (max, sum-exp) partials over s[E]
__global__ __launch_bounds__(256) void softmax_partial(
    const float* __restrict__ s, int E, float2* __restrict__ part) {
  __shared__ float mS[256], sS[256];
  int tid = threadIdx.x;
  float m = -1e30f, sum = 0.f;
  for (int i = blockIdx.x * 256 + tid; i < E; i += gridDim.x * 256) {
    float x = s[i];
    if (x > m) {
      sum = sum * __expf(m - x) + 1.f;
      m = x;
    } else {
      sum += __expf(x - m);
    }
  }
  mS[tid] = m;
  sS[tid] = sum;
  __syncthreads();
  for (int off = 128; off > 0; off >>= 1) {
    if (tid < off) {
      float m1 = mS[tid], s1 = sS[tid];
      float m2 = mS[tid + off], s2 = sS[tid + off];
      float M = fmaxf(m1, m2);
      mS[tid] = M;
      sS[tid] = s1 * __expf(m1 - M) + s2 * __expf(m2 - M);
    }
    __syncthreads();
  }
  if (tid == 0) part[blockIdx.x] = make_float2(mS[0], sS[0]);
}

// K4: final reduce of partials -> MS[0]=M, MS[1]=1/sum
__global__ __launch_bounds__(256) void softmax_final(
    const float2* __restrict__ part, int nPart, float* __restrict__ MS) {
  __shared__ float mS[256], sS[256];
  int tid = threadIdx.x;
  float m = -1e30f, sum = 0.f;
  for (int i = tid; i < nPart; i += 256) {
    float2 p = part[i];
    float M = fmaxf(m, p.x);
    sum = sum * __expf(m - M) + p.y * __expf(p.x - M);
    m = M;
  }
  mS[tid] = m;
  sS[tid] = sum;
  __syncthreads();
  for (int off = 128; off > 0; off >>= 1) {
    if (tid < off) {
      float m1 = mS[tid], s1 = sS[tid];
      float m2 = mS[tid + off], s2 = sS[tid + off];
      float M = fmaxf(m1, m2);
      mS[tid] = M;
      sS[tid] = s1 * __expf(m1 - M) + s2 * __expf(m2 - M);
    }
    __syncthreads();
  }
  if (tid == 0) {
    MS[0] = mS[0];
    MS[1] = 1.f / sS[0];
  }
}

// ---------------------------------------------------------------------------
// K5: scatter  out[src[e]] += w_e * v[tgt[e]]
__global__ __launch_bounds__(256) void scatter_edges(
    const float* __restrict__ s, const float* __restrict__ MS,
    const int* __restrict__ src, const int* __restrict__ tgt,
    const float* __restrict__ v, float* __restrict__ out) {
  int tid = threadIdx.x;
  int e = blockIdx.x * 2 + (tid >> 7);
  int d = tid & 127;
  float w = __expf(s[e] - MS[0]) * MS[1];
  int si = src[e], ti = tgt[e];
  atomicAdd(&out[(size_t)si * D + d], w * v[(size_t)ti * D + d]);
}

// ---------------------------------------------------------------------------
// K6: y = LayerNorm(h + out) * gamma + beta.  One wave per node.
__global__ __launch_bounds__(256) void layernorm_kernel(
    const float* __restrict__ out_acc, const float* __restrict__ gamma,
    const float* __restrict__ beta, float* __restrict__ y, int N) {
  int tid = threadIdx.x;
  int n = blockIdx.x * 4 + (tid >> 6);
  if (n >= N) return;
  int lane = tid & 63;
  size_t base = (size_t)n * D;
  float y0 = y[base + lane] + out_acc[base + lane];
  float y1 = y[base + 64 + lane] + out_acc[base + 64 + lane];
  float sum = y0 + y1;
  float ssq = y0 * y0 + y1 * y1;
#pragma unroll
  for (int off = 1; off < 64; off <<= 1) {
    sum += __shfl_xor(sum, off);
    ssq += __shfl_xor(ssq, off);
  }
  float mu = sum * (1.f / 128.f);
  float var = ssq * (1.f / 128.f) - mu * mu;
  float rstd = rsqrtf(var + EPS);
  y[base + lane] = gamma[lane] * (y0 - mu) * rstd + beta[lane];
  y[base + 64 + lane] = gamma[64 + lane] * (y1 - mu) * rstd + beta[64 + lane];
}

// ---------------------------------------------------------------------------
extern "C" void kernel_launch(void* const* d_in, const int* in_sizes, int n_in,
                              void* d_out, int out_size, void* d_ws,
                              size_t ws_size, hipStream_t stream) {
  const float* X  = (const float*)d_in[0];
  const float* EF = (const float*)d_in[1];
  const float* Wn = (const float*)d_in[2];
  const float* bn = (const float*)d_in[3];
  const float* Wq = (const float*)d_in[4];
  const float* bq = (const float*)d_in[5];
  const float* Wk = (const float*)d_in[6];
  const float* bk = (const float*)d_in[7];
  const float* Wv = (const float*)d_in[8];
  const float* bv = (const float*)d_in[9];
  const float* We = (const float*)d_in[10];
  const float* be = (const float*)d_in[11];
  const float* A1 = (const float*)d_in[12];
  const float* b1 = (const float*)d_in[13];
  const float* A2 = (const float*)d_in[14];
  const float* b2 = (const float*)d_in[15];
  const float* gamma = (const float*)d_in[16];
  const float* beta  = (const float*)d_in[17];
  const int* ei = (const int*)d_in[18];

  int N = in_sizes[0] / D;   // 50000
  int E = in_sizes[1] / DE;  // 400000
  const int* src = ei;
  const int* tgt = ei + E;

  float* h = (float*)d_out;  // h accumulated/normalized in place
  float* ws = (float*)d_ws;
  float* v     = ws;
  float* outa  = v + (size_t)N * D;
  float* Afold = outa + (size_t)N * D;
  float* bfold = Afold + 320 * 128;
  float* sbuf  = bfold + 128;
  float2* part = (float2*)(sbuf + E);
  float* MS    = (float*)(part + 1024);
  unsigned short* Xb  = (unsigned short*)(MS + 4);
  unsigned short* AfT = Xb + (size_t)N * D;
  unsigned short* WnT = AfT + 128 * 320;
  unsigned short* WvT = WnT + 128 * 128;

  hipMemsetAsync(outa, 0, (size_t)N * D * sizeof(float), stream);
  fold_kernel<<<321, 128, 0, stream>>>(Wq, Wk, We, A1, bq, bk, be, b1, Afold,
                                       bfold);
  pack_weights<<<160, 256, 0, stream>>>(Afold, Wn, Wv, AfT, WnT, WvT);
  cvt_to_bf16<<<(N * D / 4 + 255) / 256, 256, 0, stream>>>(X, Xb, N * D / 4);
  node_gemm_mfma<<<dim3((N + 255) / 256, 2), 256, 0, stream>>>(Xb, WnT, WvT, bn,
                                                               bv, h, v, N);
  edge_fused_mfma<<<(E + 255) / 256, 256, 0, stream>>>(Xb, EF, AfT, bfold, A2,
                                                       b2, src, tgt, sbuf, E);
  softmax_partial<<<1024, 256, 0, stream>>>(sbuf, E, part);
  softmax_final<<<1, 256, 0, stream>>>(part, 1024, MS);
  scatter_edges<<<E / 2, 256, 0, stream>>>(sbuf, MS, src, tgt, v, outa);
  layernorm_kernel<<<(N + 3) / 4, 256, 0, stream>>>(outa, gamma, beta, h, N);
}

// Round 3
// 503.544 us; speedup vs baseline: 7.4773x; 1.0898x over previous
//
#include <hip/hip_runtime.h>

// N=50000, E=400000, D=128, DE=64, H=8
#define D 128
#define DE 64
#define SLOPE 0.2f
#define EPS 1e-5f

typedef float f32x4 __attribute__((ext_vector_type(4)));
typedef short bf16x8 __attribute__((ext_vector_type(8)));

__device__ __forceinline__ float lrelu(float x) { return x > 0.f ? x : SLOPE * x; }

// fp32 -> bf16 RNE
__device__ __forceinline__ unsigned short f2bf(float x) {
  union { float f; unsigned u; } c; c.f = x;
  unsigned r = c.u + 0x7FFFu + ((c.u >> 16) & 1u);
  return (unsigned short)(r >> 16);
}

// ---------------------------------------------------------------------------
// K0: fold weights (fp32).  Afold[320][128], bfold[128]
__global__ __launch_bounds__(128) void fold_kernel(
    const float* __restrict__ Wq, const float* __restrict__ Wk,
    const float* __restrict__ We, const float* __restrict__ A1,
    const float* __restrict__ bq, const float* __restrict__ bk,
    const float* __restrict__ be, const float* __restrict__ b1,
    float* __restrict__ Afold, float* __restrict__ bfold) {
  int r = blockIdx.x;
  int j = threadIdx.x;
  if (r < 128) {
    float acc = 0.f;
    for (int t = 0; t < 128; ++t) acc += Wq[r * 128 + t] * A1[t * 128 + j];
    Afold[r * 128 + j] = acc;
  } else if (r < 256) {
    int i = r - 128;
    float acc = 0.f;
    for (int t = 0; t < 128; ++t) acc += Wk[i * 128 + t] * A1[(128 + t) * 128 + j];
    Afold[r * 128 + j] = acc;
  } else if (r < 320) {
    int i = r - 256;
    float acc = 0.f;
    for (int t = 0; t < 128; ++t) acc += We[i * 128 + t] * A1[(256 + t) * 128 + j];
    Afold[r * 128 + j] = acc;
  } else {
    float acc = b1[j];
    for (int t = 0; t < 128; ++t) {
      acc += bq[t] * A1[t * 128 + j];
      acc += bk[t] * A1[(128 + t) * 128 + j];
      acc += be[t] * A1[(256 + t) * 128 + j];
    }
    bfold[j] = acc;
  }
}

// ---------------------------------------------------------------------------
// Pack Afold -> AfT (bf16, [col][k]), Wn/Wv -> WT bf16
__global__ __launch_bounds__(256) void pack_weights(
    const float* __restrict__ Afold, const float* __restrict__ Wn,
    const float* __restrict__ Wv, unsigned short* __restrict__ AfT,
    unsigned short* __restrict__ WnT, unsigned short* __restrict__ WvT) {
  int i = blockIdx.x * 256 + threadIdx.x;
  if (i < 128 * 320) {
    int c = i / 320, k = i - c * 320;
    AfT[i] = f2bf(Afold[k * 128 + c]);
  }
  if (i < 128 * 128) {
    int c = i >> 7, k = i & 127;
    WnT[i] = f2bf(Wn[k * 128 + c]);
    WvT[i] = f2bf(Wv[k * 128 + c]);
  }
}

// X fp32 -> bf16 (row-major unchanged)
__global__ __launch_bounds__(256) void cvt_to_bf16(
    const float* __restrict__ X, unsigned short* __restrict__ Xb, int n4) {
  int i = blockIdx.x * 256 + threadIdx.x;
  if (i < n4) {
    float4 f = ((const float4*)X)[i];
    union { unsigned short us[4]; uint2 v; } u;
    u.us[0] = f2bf(f.x); u.us[1] = f2bf(f.y);
    u.us[2] = f2bf(f.z); u.us[3] = f2bf(f.w);
    ((uint2*)Xb)[i] = u.v;
  }
}

// ---------------------------------------------------------------------------
// K1: node GEMMs via MFMA.  y==0 -> h = X@Wn+bn, y==1 -> v = X@Wv+bv
__global__ __launch_bounds__(256, 2) void node_gemm_mfma(
    const unsigned short* __restrict__ Xb, const unsigned short* __restrict__ WnT,
    const unsigned short* __restrict__ WvT, const float* __restrict__ bn,
    const float* __restrict__ bv, float* __restrict__ h, float* __restrict__ v,
    int Nn) {
  __shared__ unsigned short As[256 * 40];  // stride 40 bf16 (+8 pad)
  __shared__ unsigned short Bs[128 * 40];
  __shared__ float bS[128];
  const unsigned short* WT;
  const float* bb;
  float* O;
  if (blockIdx.y == 0) { WT = WnT; bb = bn; O = h; }
  else                 { WT = WvT; bb = bv; O = v; }
  const int t = threadIdx.x;
  if (t < 128) bS[t] = bb[t];
  const int seg = t & 3, arow = t >> 2;
  const int m0 = blockIdx.x * 256;
  int rIdx[4];
#pragma unroll
  for (int l = 0; l < 4; ++l) rIdx[l] = min(m0 + arow + 64 * l, Nn - 1);
  uint4 avA[4], avB[2];
#pragma unroll
  for (int l = 0; l < 4; ++l)
    avA[l] = *(const uint4*)(Xb + (size_t)rIdx[l] * 128 + seg * 8);
#pragma unroll
  for (int l = 0; l < 2; ++l)
    avB[l] = *(const uint4*)(WT + (arow + 64 * l) * 128 + seg * 8);
  f32x4 acc[4][8];
#pragma unroll
  for (int mt = 0; mt < 4; ++mt)
#pragma unroll
    for (int nt = 0; nt < 8; ++nt) acc[mt][nt] = (f32x4)(0.f);
  const int lane = t & 63, wv = t >> 6, l15 = lane & 15, quad = lane >> 4;
  for (int ch = 0; ch < 4; ++ch) {
#pragma unroll
    for (int l = 0; l < 4; ++l)
      *(uint4*)&As[(arow + 64 * l) * 40 + seg * 8] = avA[l];
#pragma unroll
    for (int l = 0; l < 2; ++l)
      *(uint4*)&Bs[(arow + 64 * l) * 40 + seg * 8] = avB[l];
    __syncthreads();
    if (ch < 3) {
      int o = (ch + 1) * 32 + seg * 8;
#pragma unroll
      for (int l = 0; l < 4; ++l)
        avA[l] = *(const uint4*)(Xb + (size_t)rIdx[l] * 128 + o);
#pragma unroll
      for (int l = 0; l < 2; ++l)
        avB[l] = *(const uint4*)(WT + (arow + 64 * l) * 128 + o);
    }
    bf16x8 af[4];
#pragma unroll
    for (int mt = 0; mt < 4; ++mt)
      af[mt] = *(const bf16x8*)&As[(wv * 64 + mt * 16 + l15) * 40 + quad * 8];
#pragma unroll
    for (int nt = 0; nt < 8; ++nt) {
      bf16x8 bfr = *(const bf16x8*)&Bs[(nt * 16 + l15) * 40 + quad * 8];
#pragma unroll
      for (int mt = 0; mt < 4; ++mt)
        acc[mt][nt] =
            __builtin_amdgcn_mfma_f32_16x16x32_bf16(af[mt], bfr, acc[mt][nt], 0, 0, 0);
    }
    __syncthreads();
  }
#pragma unroll
  for (int mt = 0; mt < 4; ++mt) {
    int rowb = m0 + wv * 64 + mt * 16 + quad * 4;
#pragma unroll
    for (int nt = 0; nt < 8; ++nt) {
      int col = nt * 16 + l15;
      float b = bS[col];
#pragma unroll
      for (int r = 0; r < 4; ++r) {
        int rg = rowb + r;
        if (rg < Nn) O[(size_t)rg * 128 + col] = acc[mt][nt][r] + b;
      }
    }
  }
}

// ---------------------------------------------------------------------------
// K2: fused edge pipeline via MFMA (unchanged from R2).
__global__ __launch_bounds__(256, 2) void edge_fused_mfma(
    const unsigned short* __restrict__ Xb, const float* __restrict__ EF,
    const unsigned short* __restrict__ AfT, const float* __restrict__ bfold,
    const float* __restrict__ A2, const float* __restrict__ b2,
    const int* __restrict__ src, const int* __restrict__ tgt,
    float* __restrict__ s_out, int E) {
  __shared__ unsigned short As[256 * 40];
  __shared__ unsigned short Bs[128 * 40];
  __shared__ float A2s[128 * 9];
  __shared__ float bfS[128];
  __shared__ float b2s[8];
  __shared__ int sIdxS[256], sIdxT[256];
  const int t = threadIdx.x;
  const int e0 = blockIdx.x * 256;
  {
    int ec = min(e0 + t, E - 1);
    sIdxS[t] = src[ec];
    sIdxT[t] = tgt[ec];
    if (t < 128) bfS[t] = bfold[t];
    if (t < 8) b2s[t] = b2[t];
#pragma unroll
    for (int l = 0; l < 4; ++l) {
      int i = t + l * 256;
      A2s[(i >> 3) * 9 + (i & 7)] = A2[i];
    }
  }
  __syncthreads();
  const int seg = t & 3, arow = t >> 2;
  int si[4], ti[4], ecl[4];
#pragma unroll
  for (int l = 0; l < 4; ++l) {
    si[l] = sIdxS[arow + 64 * l];
    ti[l] = sIdxT[arow + 64 * l];
    ecl[l] = min(e0 + arow + 64 * l, E - 1);
  }
  uint4 avA[4], avB[2];
#pragma unroll
  for (int l = 0; l < 4; ++l)
    avA[l] = *(const uint4*)(Xb + (size_t)si[l] * 128 + seg * 8);
#pragma unroll
  for (int l = 0; l < 2; ++l)
    avB[l] = *(const uint4*)(AfT + (arow + 64 * l) * 320 + seg * 8);
  f32x4 acc[4][8];
#pragma unroll
  for (int mt = 0; mt < 4; ++mt)
#pragma unroll
    for (int nt = 0; nt < 8; ++nt) acc[mt][nt] = (f32x4)(0.f);
  const int lane = t & 63, wv = t >> 6, l15 = lane & 15, quad = lane >> 4;

  for (int ch = 0; ch < 10; ++ch) {
#pragma unroll
    for (int l = 0; l < 4; ++l)
      *(uint4*)&As[(arow + 64 * l) * 40 + seg * 8] = avA[l];
#pragma unroll
    for (int l = 0; l < 2; ++l)
      *(uint4*)&Bs[(arow + 64 * l) * 40 + seg * 8] = avB[l];
    __syncthreads();
    if (ch < 9) {
      int cn = ch + 1;
      if (cn < 4) {
        int o = cn * 32 + seg * 8;
#pragma unroll
        for (int l = 0; l < 4; ++l)
          avA[l] = *(const uint4*)(Xb + (size_t)si[l] * 128 + o);
      } else if (cn < 8) {
        int o = (cn - 4) * 32 + seg * 8;
#pragma unroll
        for (int l = 0; l < 4; ++l)
          avA[l] = *(const uint4*)(Xb + (size_t)ti[l] * 128 + o);
      } else {
        int o = (cn - 8) * 32 + seg * 8;
#pragma unroll
        for (int l = 0; l < 4; ++l) {
          const float* p = EF + (size_t)ecl[l] * 64 + o;
          float4 f0 = *(const float4*)p;
          float4 f1 = *(const float4*)(p + 4);
          union { unsigned short us[8]; uint4 v; } u;
          u.us[0] = f2bf(f0.x); u.us[1] = f2bf(f0.y);
          u.us[2] = f2bf(f0.z); u.us[3] = f2bf(f0.w);
          u.us[4] = f2bf(f1.x); u.us[5] = f2bf(f1.y);
          u.us[6] = f2bf(f1.z); u.us[7] = f2bf(f1.w);
          avA[l] = u.v;
        }
      }
      int ob = cn * 32 + seg * 8;
#pragma unroll
      for (int l = 0; l < 2; ++l)
        avB[l] = *(const uint4*)(AfT + (arow + 64 * l) * 320 + ob);
    }
    bf16x8 af[4];
#pragma unroll
    for (int mt = 0; mt < 4; ++mt)
      af[mt] = *(const bf16x8*)&As[(wv * 64 + mt * 16 + l15) * 40 + quad * 8];
#pragma unroll
    for (int nt = 0; nt < 8; ++nt) {
      bf16x8 bfr = *(const bf16x8*)&Bs[(nt * 16 + l15) * 40 + quad * 8];
#pragma unroll
      for (int mt = 0; mt < 4; ++mt)
        acc[mt][nt] =
            __builtin_amdgcn_mfma_f32_16x16x32_bf16(af[mt], bfr, acc[mt][nt], 0, 0, 0);
    }
    __syncthreads();
  }

  float bfv[8];
#pragma unroll
  for (int nt = 0; nt < 8; ++nt) bfv[nt] = bfS[nt * 16 + l15];
#pragma unroll
  for (int mt = 0; mt < 4; ++mt)
#pragma unroll
    for (int nt = 0; nt < 8; ++nt)
#pragma unroll
      for (int r = 0; r < 4; ++r)
        acc[mt][nt][r] = lrelu(acc[mt][nt][r] + bfv[nt]);
  float tacc[4][4];
#pragma unroll
  for (int mt = 0; mt < 4; ++mt)
#pragma unroll
    for (int r = 0; r < 4; ++r) tacc[mt][r] = 0.f;
  for (int hh = 0; hh < 8; ++hh) {
    float a2v[8];
#pragma unroll
    for (int nt = 0; nt < 8; ++nt) a2v[nt] = A2s[nt * 144 + l15 * 9 + hh];
    float b2h = b2s[hh];
#pragma unroll
    for (int mt = 0; mt < 4; ++mt)
#pragma unroll
      for (int r = 0; r < 4; ++r) {
        float p = 0.f;
#pragma unroll
        for (int nt = 0; nt < 8; ++nt) p += acc[mt][nt][r] * a2v[nt];
        p += __shfl_xor(p, 1);
        p += __shfl_xor(p, 2);
        p += __shfl_xor(p, 4);
        p += __shfl_xor(p, 8);
        tacc[mt][r] += lrelu(p + b2h);
      }
  }
  if (l15 == 0) {
#pragma unroll
    for (int mt = 0; mt < 4; ++mt)
#pragma unroll
      for (int r = 0; r < 4; ++r) {
        int e = e0 + wv * 64 + mt * 16 + quad * 4 + r;
        if (e < E) s_out[e] = tacc[mt][r] * 0.125f;
      }
  }
}

// ---------------------------------------------------------------------------
// K3/K4: global softmax reduction
__global__ __launch_bounds__(256) void softmax_partial(
    const float* __restrict__ s, int E, float2* __restrict__ part) {
  __shared__ float mS[256], sS[256];
  int tid = threadIdx.x;
  float m = -1e30f, sum = 0.f;
  for (int i = blockIdx.x * 256 + tid; i < E; i += gridDim.x * 256) {
    float x = s[i];
    if (x > m) {
      sum = sum * __expf(m - x) + 1.f;
      m = x;
    } else {
      sum += __expf(x - m);
    }
  }
  mS[tid] = m;
  sS[tid] = sum;
  __syncthreads();
  for (int off = 128; off > 0; off >>= 1) {
    if (tid < off) {
      float m1 = mS[tid], s1 = sS[tid];
      float m2 = mS[tid + off], s2 = sS[tid + off];
      float M = fmaxf(m1, m2);
      mS[tid] = M;
      sS[tid] = s1 * __expf(m1 - M) + s2 * __expf(m2 - M);
    }
    __syncthreads();
  }
  if (tid == 0) part[blockIdx.x] = make_float2(mS[0], sS[0]);
}

__global__ __launch_bounds__(256) void softmax_final(
    const float2* __restrict__ part, int nPart, float* __restrict__ MS) {
  __shared__ float mS[256], sS[256];
  int tid = threadIdx.x;
  float m = -1e30f, sum = 0.f;
  for (int i = tid; i < nPart; i += 256) {
    float2 p = part[i];
    float M = fmaxf(m, p.x);
    sum = sum * __expf(m - M) + p.y * __expf(p.x - M);
    m = M;
  }
  mS[tid] = m;
  sS[tid] = sum;
  __syncthreads();
  for (int off = 128; off > 0; off >>= 1) {
    if (tid < off) {
      float m1 = mS[tid], s1 = sS[tid];
      float m2 = mS[tid + off], s2 = sS[tid + off];
      float M = fmaxf(m1, m2);
      mS[tid] = M;
      sS[tid] = s1 * __expf(m1 - M) + s2 * __expf(m2 - M);
    }
    __syncthreads();
  }
  if (tid == 0) {
    MS[0] = mS[0];
    MS[1] = 1.f / sS[0];
  }
}

// w[e] = exp(s[e]-M) / sum   (in place over sbuf)
__global__ __launch_bounds__(256) void wcompute(float* __restrict__ s,
                                               const float* __restrict__ MS,
                                               int E) {
  int e = blockIdx.x * 256 + threadIdx.x;
  if (e < E) s[e] = __expf(s[e] - MS[0]) * MS[1];
}

// ---------------------------------------------------------------------------
// CSR build: deg histogram -> 3-step exclusive scan -> bucket fill
__global__ __launch_bounds__(256) void count_deg(const int* __restrict__ src,
                                                 int* __restrict__ deg, int E) {
  int e = blockIdx.x * 256 + threadIdx.x;
  if (e < E) atomicAdd(&deg[src[e]], 1);
}

__global__ __launch_bounds__(256) void scan1(const int* __restrict__ deg,
                                             int* __restrict__ incl,
                                             int* __restrict__ bsum, int N) {
  __shared__ int sh[256];
  int tid = threadIdx.x;
  int i = blockIdx.x * 256 + tid;
  sh[tid] = (i < N) ? deg[i] : 0;
  __syncthreads();
  for (int off = 1; off < 256; off <<= 1) {
    int tv = (tid >= off) ? sh[tid - off] : 0;
    __syncthreads();
    sh[tid] += tv;
    __syncthreads();
  }
  if (i < N) incl[i] = sh[tid];
  if (tid == 255) bsum[blockIdx.x] = sh[255];
}

__global__ __launch_bounds__(256) void scan2(int* __restrict__ bsum, int nb) {
  __shared__ int sh[256];
  int tid = threadIdx.x;
  sh[tid] = (tid < nb) ? bsum[tid] : 0;
  __syncthreads();
  for (int off = 1; off < 256; off <<= 1) {
    int tv = (tid >= off) ? sh[tid - off] : 0;
    __syncthreads();
    sh[tid] += tv;
    __syncthreads();
  }
  if (tid < nb) bsum[tid] = sh[tid];
}

__global__ __launch_bounds__(256) void scan3(const int* __restrict__ deg,
                                             const int* __restrict__ incl,
                                             const int* __restrict__ bsum,
                                             int* __restrict__ offs,
                                             int* __restrict__ cursor, int N,
                                             int E) {
  int i = blockIdx.x * 256 + threadIdx.x;
  if (i >= N) return;
  int base = (blockIdx.x > 0) ? bsum[blockIdx.x - 1] : 0;
  int ex = incl[i] - deg[i] + base;
  offs[i] = ex;
  cursor[i] = ex;
  if (i == N - 1) offs[N] = E;
}

// fill: cwt[j] = (tgt[e], w[e]) bucketed by src[e]
__global__ __launch_bounds__(256) void fill_csr(
    const int* __restrict__ src, const int* __restrict__ tgt,
    const float* __restrict__ w, int* __restrict__ cursor,
    int2* __restrict__ cwt, int E) {
  int e = blockIdx.x * 256 + threadIdx.x;
  if (e >= E) return;
  int s_ = src[e];
  int j = atomicAdd(&cursor[s_], 1);
  cwt[j] = make_int2(tgt[e], __float_as_int(w[e]));
}

// ---------------------------------------------------------------------------
// K5: fused gather + layernorm.  128 threads (2 waves) per node, 2 nodes/block.
// y (=d_out) holds h; updated in place with LN(h + Σ w·v[tgt]).
__global__ __launch_bounds__(256) void gather_ln(
    const int* __restrict__ offs, const int2* __restrict__ cwt,
    const float* __restrict__ v, const float* __restrict__ gamma,
    const float* __restrict__ beta, float* __restrict__ y, int N) {
  __shared__ float wsum[4], wssq[4];
  int tid = threadIdx.x;
  int local = tid >> 7;
  int n = blockIdx.x * 2 + local;
  int d = tid & 127;
  float acc = 0.f;
  if (n < N) {
    int beg = offs[n], end = offs[n + 1];
    for (int j = beg; j < end; ++j) {
      int2 p = cwt[j];
      acc += __int_as_float(p.y) * v[(size_t)p.x * 128 + d];
    }
  }
  size_t base = (size_t)n * 128 + d;
  float yv = (n < N) ? (y[base] + acc) : 0.f;
  float sum = yv, ssq = yv * yv;
#pragma unroll
  for (int off = 1; off < 64; off <<= 1) {
    sum += __shfl_xor(sum, off);
    ssq += __shfl_xor(ssq, off);
  }
  int wvid = tid >> 6;
  if ((tid & 63) == 0) { wsum[wvid] = sum; wssq[wvid] = ssq; }
  __syncthreads();
  if (n < N) {
    float S = wsum[local * 2] + wsum[local * 2 + 1];
    float Q = wssq[local * 2] + wssq[local * 2 + 1];
    float mu = S * (1.f / 128.f);
    float var = Q * (1.f / 128.f) - mu * mu;
    float rstd = rsqrtf(var + EPS);
    y[base] = gamma[d] * (yv - mu) * rstd + beta[d];
  }
}

// ---------------------------------------------------------------------------
extern "C" void kernel_launch(void* const* d_in, const int* in_sizes, int n_in,
                              void* d_out, int out_size, void* d_ws,
                              size_t ws_size, hipStream_t stream) {
  const float* X  = (const float*)d_in[0];
  const float* EF = (const float*)d_in[1];
  const float* Wn = (const float*)d_in[2];
  const float* bn = (const float*)d_in[3];
  const float* Wq = (const float*)d_in[4];
  const float* bq = (const float*)d_in[5];
  const float* Wk = (const float*)d_in[6];
  const float* bk = (const float*)d_in[7];
  const float* Wv = (const float*)d_in[8];
  const float* bv = (const float*)d_in[9];
  const float* We = (const float*)d_in[10];
  const float* be = (const float*)d_in[11];
  const float* A1 = (const float*)d_in[12];
  const float* b1 = (const float*)d_in[13];
  const float* A2 = (const float*)d_in[14];
  const float* b2 = (const float*)d_in[15];
  const float* gamma = (const float*)d_in[16];
  const float* beta  = (const float*)d_in[17];
  const int* ei = (const int*)d_in[18];

  int N = in_sizes[0] / D;   // 50000
  int E = in_sizes[1] / DE;  // 400000
  const int* src = ei;
  const int* tgt = ei + E;

  float* h = (float*)d_out;  // h accumulated/normalized in place
  float* ws = (float*)d_ws;
  float* v     = ws;                                   // N*D
  float* Afold = v + (size_t)N * D;                    // 320*128
  float* bfold = Afold + 320 * 128;                    // 128
  float* sbuf  = bfold + 128;                          // E
  float2* part = (float2*)(sbuf + E);                  // 1024
  float* MS    = (float*)(part + 1024);                // 4
  unsigned short* Xb  = (unsigned short*)(MS + 4);     // N*D
  unsigned short* AfT = Xb + (size_t)N * D;            // 128*320
  unsigned short* WnT = AfT + 128 * 320;               // 128*128
  unsigned short* WvT = WnT + 128 * 128;               // 128*128
  int* deg    = (int*)(WvT + 128 * 128);               // N
  int* incl   = deg + N;                               // N
  int* bsum   = incl + N;                              // 256
  int* cursor = bsum + 256;                            // N
  int2* cwt   = (int2*)(cursor + N);                   // E (8B each)
  int* offs   = (int*)(cwt + E);                       // N+1

  int nbScan = (N + 255) / 256;  // 196 (must be <= 256)

  hipMemsetAsync(deg, 0, (size_t)N * sizeof(int), stream);
  fold_kernel<<<321, 128, 0, stream>>>(Wq, Wk, We, A1, bq, bk, be, b1, Afold,
                                       bfold);
  pack_weights<<<160, 256, 0, stream>>>(Afold, Wn, Wv, AfT, WnT, WvT);
  cvt_to_bf16<<<(N * D / 4 + 255) / 256, 256, 0, stream>>>(X, Xb, N * D / 4);
  node_gemm_mfma<<<dim3((N + 255) / 256, 2), 256, 0, stream>>>(Xb, WnT, WvT, bn,
                                                               bv, h, v, N);
  count_deg<<<(E + 255) / 256, 256, 0, stream>>>(src, deg, E);
  scan1<<<nbScan, 256, 0, stream>>>(deg, incl, bsum, N);
  scan2<<<1, 256, 0, stream>>>(bsum, nbScan);
  scan3<<<nbScan, 256, 0, stream>>>(deg, incl, bsum, offs, cursor, N, E);
  edge_fused_mfma<<<(E + 255) / 256, 256, 0, stream>>>(Xb, EF, AfT, bfold, A2,
                                                       b2, src, tgt, sbuf, E);
  softmax_partial<<<1024, 256, 0, stream>>>(sbuf, E, part);
  softmax_final<<<1, 256, 0, stream>>>(part, 1024, MS);
  wcompute<<<(E + 255) / 256, 256, 0, stream>>>(sbuf, MS, E);
  fill_csr<<<(E + 255) / 256, 256, 0, stream>>>(src, tgt, sbuf, cursor, cwt, E);
  gather_ln<<<(N + 1) / 2, 256, 0, stream>>>(offs, cwt, v, gamma, beta, h, N);
}

// Round 4
// 436.800 us; speedup vs baseline: 8.6199x; 1.1528x over previous
//
#include <hip/hip_runtime.h>

// N=50000, E=400000, D=128, DE=64, H=8
#define D 128
#define DE 64
#define SLOPE 0.2f
#define EPS 1e-5f

typedef float f32x4 __attribute__((ext_vector_type(4)));
typedef short bf16x8 __attribute__((ext_vector_type(8)));

__device__ __forceinline__ float lrelu(float x) { return x > 0.f ? x : SLOPE * x; }

// fp32 -> bf16 RNE
__device__ __forceinline__ unsigned short f2bf(float x) {
  union { float f; unsigned u; } c; c.f = x;
  unsigned r = c.u + 0x7FFFu + ((c.u >> 16) & 1u);
  return (unsigned short)(r >> 16);
}
__device__ __forceinline__ float bf2f(unsigned short u) {
  return __uint_as_float(((unsigned)u) << 16);
}

// ---------------------------------------------------------------------------
// K0: fold weights + pack all bf16 operand tables in one kernel.
//  blocks 0..127   : AfqT[j][r]   = bf16(Wq@A1q)      (col-major k-contig)
//  blocks 128..255 : AfkT[j][r-128]
//  blocks 256..319 : AfeT[j][r-256]   (K=64)
//  block  320      : bfold[j] = b1 + bq@A1q + bk@A1k + be@A1e   (fp32)
//  blocks 321..448 : WnT[c][k] = bf16(Wn[k][c])
//  blocks 449..576 : WvT[c][k] = bf16(Wv[k][c])
__global__ __launch_bounds__(128) void fold_pack(
    const float* __restrict__ Wq, const float* __restrict__ Wk,
    const float* __restrict__ We, const float* __restrict__ A1,
    const float* __restrict__ bq, const float* __restrict__ bk,
    const float* __restrict__ be, const float* __restrict__ b1,
    const float* __restrict__ Wn, const float* __restrict__ Wv,
    unsigned short* __restrict__ AfqT, unsigned short* __restrict__ AfkT,
    unsigned short* __restrict__ AfeT, float* __restrict__ bfold,
    unsigned short* __restrict__ WnT, unsigned short* __restrict__ WvT) {
  int r = blockIdx.x;
  int j = threadIdx.x;
  if (r < 128) {
    float acc = 0.f;
    for (int t = 0; t < 128; ++t) acc += Wq[r * 128 + t] * A1[t * 128 + j];
    AfqT[j * 128 + r] = f2bf(acc);
  } else if (r < 256) {
    int k = r - 128;
    float acc = 0.f;
    for (int t = 0; t < 128; ++t) acc += Wk[k * 128 + t] * A1[(128 + t) * 128 + j];
    AfkT[j * 128 + k] = f2bf(acc);
  } else if (r < 320) {
    int k = r - 256;
    float acc = 0.f;
    for (int t = 0; t < 128; ++t) acc += We[k * 128 + t] * A1[(256 + t) * 128 + j];
    AfeT[j * 64 + k] = f2bf(acc);
  } else if (r == 320) {
    float acc = b1[j];
    for (int t = 0; t < 128; ++t) {
      acc += bq[t] * A1[t * 128 + j];
      acc += bk[t] * A1[(128 + t) * 128 + j];
      acc += be[t] * A1[(256 + t) * 128 + j];
    }
    bfold[j] = acc;
  } else if (r < 449) {
    int c = r - 321;
    WnT[c * 128 + j] = f2bf(Wn[j * 128 + c]);
  } else {
    int c = r - 449;
    WvT[c * 128 + j] = f2bf(Wv[j * 128 + c]);
  }
}

// X fp32 -> bf16 (row-major unchanged)
__global__ __launch_bounds__(256) void cvt_to_bf16(
    const float* __restrict__ X, unsigned short* __restrict__ Xb, int n4) {
  int i = blockIdx.x * 256 + threadIdx.x;
  if (i < n4) {
    float4 f = ((const float4*)X)[i];
    union { unsigned short us[4]; uint2 v; } u;
    u.us[0] = f2bf(f.x); u.us[1] = f2bf(f.y);
    u.us[2] = f2bf(f.z); u.us[3] = f2bf(f.w);
    ((uint2*)Xb)[i] = u.v;
  }
}

// ---------------------------------------------------------------------------
// K1: node GEMMs via MFMA.
//  y=0: h = X@Wn+bn (fp32, d_out)     y=1: v = X@Wv+bv (fp32)
//  y=2: q2p = bf16(X@Af_q) permuted   y=3: k2p = bf16(X@Af_k) permuted
// Permuted layout: q2p[n*128 + l15*8 + nt] holds col (nt*16+l15) so the edge
// epilogue reads each lane's 8 values with ONE 16-byte load.
__global__ __launch_bounds__(256, 2) void node_gemm_mfma(
    const unsigned short* __restrict__ Xb, const unsigned short* __restrict__ WnT,
    const unsigned short* __restrict__ WvT, const unsigned short* __restrict__ AfqT,
    const unsigned short* __restrict__ AfkT, const float* __restrict__ bn,
    const float* __restrict__ bv, float* __restrict__ h, float* __restrict__ v,
    unsigned short* __restrict__ q2p, unsigned short* __restrict__ k2p, int Nn) {
  __shared__ unsigned short As[256 * 40];  // stride 40 bf16 (+8 pad)
  __shared__ unsigned short Bs[128 * 40];
  __shared__ float bS[128];
  const unsigned short* WT;
  const float* bb = nullptr;
  float* O = nullptr;
  unsigned short* Ob = nullptr;
  switch (blockIdx.y) {
    case 0: WT = WnT; bb = bn; O = h; break;
    case 1: WT = WvT; bb = bv; O = v; break;
    case 2: WT = AfqT; Ob = q2p; break;
    default: WT = AfkT; Ob = k2p; break;
  }
  const int t = threadIdx.x;
  if (t < 128) bS[t] = bb ? bb[t] : 0.f;
  const int seg = t & 3, arow = t >> 2;
  const int m0 = blockIdx.x * 256;
  int rIdx[4];
#pragma unroll
  for (int l = 0; l < 4; ++l) rIdx[l] = min(m0 + arow + 64 * l, Nn - 1);
  uint4 avA[4], avB[2];
#pragma unroll
  for (int l = 0; l < 4; ++l)
    avA[l] = *(const uint4*)(Xb + (size_t)rIdx[l] * 128 + seg * 8);
#pragma unroll
  for (int l = 0; l < 2; ++l)
    avB[l] = *(const uint4*)(WT + (arow + 64 * l) * 128 + seg * 8);
  f32x4 acc[4][8];
#pragma unroll
  for (int mt = 0; mt < 4; ++mt)
#pragma unroll
    for (int nt = 0; nt < 8; ++nt) acc[mt][nt] = (f32x4)(0.f);
  const int lane = t & 63, wv = t >> 6, l15 = lane & 15, quad = lane >> 4;
  for (int ch = 0; ch < 4; ++ch) {
#pragma unroll
    for (int l = 0; l < 4; ++l)
      *(uint4*)&As[(arow + 64 * l) * 40 + seg * 8] = avA[l];
#pragma unroll
    for (int l = 0; l < 2; ++l)
      *(uint4*)&Bs[(arow + 64 * l) * 40 + seg * 8] = avB[l];
    __syncthreads();
    if (ch < 3) {
      int o = (ch + 1) * 32 + seg * 8;
#pragma unroll
      for (int l = 0; l < 4; ++l)
        avA[l] = *(const uint4*)(Xb + (size_t)rIdx[l] * 128 + o);
#pragma unroll
      for (int l = 0; l < 2; ++l)
        avB[l] = *(const uint4*)(WT + (arow + 64 * l) * 128 + o);
    }
    bf16x8 af[4];
#pragma unroll
    for (int mt = 0; mt < 4; ++mt)
      af[mt] = *(const bf16x8*)&As[(wv * 64 + mt * 16 + l15) * 40 + quad * 8];
#pragma unroll
    for (int nt = 0; nt < 8; ++nt) {
      bf16x8 bfr = *(const bf16x8*)&Bs[(nt * 16 + l15) * 40 + quad * 8];
#pragma unroll
      for (int mt = 0; mt < 4; ++mt)
        acc[mt][nt] =
            __builtin_amdgcn_mfma_f32_16x16x32_bf16(af[mt], bfr, acc[mt][nt], 0, 0, 0);
    }
    __syncthreads();
  }
#pragma unroll
  for (int mt = 0; mt < 4; ++mt) {
    int rowb = m0 + wv * 64 + mt * 16 + quad * 4;
#pragma unroll
    for (int nt = 0; nt < 8; ++nt) {
      int col = nt * 16 + l15;
      float b = bS[col];
#pragma unroll
      for (int r = 0; r < 4; ++r) {
        int rg = rowb + r;
        if (rg < Nn) {
          if (O) O[(size_t)rg * 128 + col] = acc[mt][nt][r] + b;
          else   Ob[(size_t)rg * 128 + l15 * 8 + nt] = f2bf(acc[mt][nt][r]);
        }
      }
    }
  }
}

// ---------------------------------------------------------------------------
// K2: streaming edge pipeline.
//  e2 = EF@Af_e (MFMA, K=64, NO gathers in K-loop)
//  hmid = lrelu(e2 + q2p[src] + k2p[tgt] + bfold)  (epilogue gathers, 16B/row)
//  s[e] = mean_h lrelu(hmid @ A2 + b2)
__global__ __launch_bounds__(256, 2) void edge_fused2(
    const float* __restrict__ EF, const unsigned short* __restrict__ AfeT,
    const float* __restrict__ bfold, const float* __restrict__ A2,
    const float* __restrict__ b2, const unsigned short* __restrict__ q2p,
    const unsigned short* __restrict__ k2p, const int* __restrict__ src,
    const int* __restrict__ tgt, float* __restrict__ s_out, int E) {
  __shared__ unsigned short As[256 * 40];
  __shared__ unsigned short Bs[128 * 40];
  __shared__ float A2s[128 * 9];
  __shared__ float bfS[128];
  __shared__ float b2s[8];
  __shared__ int sIdxS[256], sIdxT[256];
  const int t = threadIdx.x;
  const int e0 = blockIdx.x * 256;
  {
    int ec = min(e0 + t, E - 1);
    sIdxS[t] = src[ec];
    sIdxT[t] = tgt[ec];
    if (t < 128) bfS[t] = bfold[t];
    if (t < 8) b2s[t] = b2[t];
#pragma unroll
    for (int l = 0; l < 4; ++l) {
      int i = t + l * 256;
      A2s[(i >> 3) * 9 + (i & 7)] = A2[i];
    }
  }
  const int seg = t & 3, arow = t >> 2;
  int ecl[4];
#pragma unroll
  for (int l = 0; l < 4; ++l) ecl[l] = min(e0 + arow + 64 * l, E - 1);
  uint4 avA[4], avB[2];
#pragma unroll
  for (int l = 0; l < 4; ++l) {
    const float* p = EF + (size_t)ecl[l] * 64 + seg * 8;
    float4 f0 = *(const float4*)p;
    float4 f1 = *(const float4*)(p + 4);
    union { unsigned short us[8]; uint4 v; } u;
    u.us[0] = f2bf(f0.x); u.us[1] = f2bf(f0.y);
    u.us[2] = f2bf(f0.z); u.us[3] = f2bf(f0.w);
    u.us[4] = f2bf(f1.x); u.us[5] = f2bf(f1.y);
    u.us[6] = f2bf(f1.z); u.us[7] = f2bf(f1.w);
    avA[l] = u.v;
  }
#pragma unroll
  for (int l = 0; l < 2; ++l)
    avB[l] = *(const uint4*)(AfeT + (arow + 64 * l) * 64 + seg * 8);
  f32x4 acc[4][8];
#pragma unroll
  for (int mt = 0; mt < 4; ++mt)
#pragma unroll
    for (int nt = 0; nt < 8; ++nt) acc[mt][nt] = (f32x4)(0.f);
  const int lane = t & 63, wv = t >> 6, l15 = lane & 15, quad = lane >> 4;

#pragma unroll
  for (int ch = 0; ch < 2; ++ch) {
#pragma unroll
    for (int l = 0; l < 4; ++l)
      *(uint4*)&As[(arow + 64 * l) * 40 + seg * 8] = avA[l];
#pragma unroll
    for (int l = 0; l < 2; ++l)
      *(uint4*)&Bs[(arow + 64 * l) * 40 + seg * 8] = avB[l];
    __syncthreads();
    if (ch == 0) {
      int o = 32 + seg * 8;
#pragma unroll
      for (int l = 0; l < 4; ++l) {
        const float* p = EF + (size_t)ecl[l] * 64 + o;
        float4 f0 = *(const float4*)p;
        float4 f1 = *(const float4*)(p + 4);
        union { unsigned short us[8]; uint4 v; } u;
        u.us[0] = f2bf(f0.x); u.us[1] = f2bf(f0.y);
        u.us[2] = f2bf(f0.z); u.us[3] = f2bf(f0.w);
        u.us[4] = f2bf(f1.x); u.us[5] = f2bf(f1.y);
        u.us[6] = f2bf(f1.z); u.us[7] = f2bf(f1.w);
        avA[l] = u.v;
      }
#pragma unroll
      for (int l = 0; l < 2; ++l)
        avB[l] = *(const uint4*)(AfeT + (arow + 64 * l) * 64 + o);
    }
    bf16x8 af[4];
#pragma unroll
    for (int mt = 0; mt < 4; ++mt)
      af[mt] = *(const bf16x8*)&As[(wv * 64 + mt * 16 + l15) * 40 + quad * 8];
#pragma unroll
    for (int nt = 0; nt < 8; ++nt) {
      bf16x8 bfr = *(const bf16x8*)&Bs[(nt * 16 + l15) * 40 + quad * 8];
#pragma unroll
      for (int mt = 0; mt < 4; ++mt)
        acc[mt][nt] =
            __builtin_amdgcn_mfma_f32_16x16x32_bf16(af[mt], bfr, acc[mt][nt], 0, 0, 0);
    }
    if (ch == 0) __syncthreads();
  }

  // epilogue: gather q2/k2 rows (one 16B load each), bias + lrelu
  float bfv[8];
#pragma unroll
  for (int nt = 0; nt < 8; ++nt) bfv[nt] = bfS[nt * 16 + l15];
#pragma unroll
  for (int mt = 0; mt < 4; ++mt) {
#pragma unroll
    for (int r = 0; r < 4; ++r) {
      int erow = wv * 64 + mt * 16 + quad * 4 + r;
      int si = sIdxS[erow], ti = sIdxT[erow];
      uint4 qv = *(const uint4*)(q2p + (size_t)si * 128 + l15 * 8);
      uint4 kv = *(const uint4*)(k2p + (size_t)ti * 128 + l15 * 8);
      const unsigned short* qs = (const unsigned short*)&qv;
      const unsigned short* ks = (const unsigned short*)&kv;
#pragma unroll
      for (int nt = 0; nt < 8; ++nt)
        acc[mt][nt][r] =
            lrelu(acc[mt][nt][r] + bf2f(qs[nt]) + bf2f(ks[nt]) + bfv[nt]);
    }
  }
  // head stage: s = mean_h lrelu(hmid @ A2 + b2)
  float tacc[4][4];
#pragma unroll
  for (int mt = 0; mt < 4; ++mt)
#pragma unroll
    for (int r = 0; r < 4; ++r) tacc[mt][r] = 0.f;
  for (int hh = 0; hh < 8; ++hh) {
    float a2v[8];
#pragma unroll
    for (int nt = 0; nt < 8; ++nt) a2v[nt] = A2s[nt * 144 + l15 * 9 + hh];
    float b2h = b2s[hh];
#pragma unroll
    for (int mt = 0; mt < 4; ++mt)
#pragma unroll
      for (int r = 0; r < 4; ++r) {
        float p = 0.f;
#pragma unroll
        for (int nt = 0; nt < 8; ++nt) p += acc[mt][nt][r] * a2v[nt];
        p += __shfl_xor(p, 1);
        p += __shfl_xor(p, 2);
        p += __shfl_xor(p, 4);
        p += __shfl_xor(p, 8);
        tacc[mt][r] += lrelu(p + b2h);
      }
  }
  if (l15 == 0) {
#pragma unroll
    for (int mt = 0; mt < 4; ++mt)
#pragma unroll
      for (int r = 0; r < 4; ++r) {
        int e = e0 + wv * 64 + mt * 16 + quad * 4 + r;
        if (e < E) s_out[e] = tacc[mt][r] * 0.125f;
      }
  }
}

// ---------------------------------------------------------------------------
// K3/K4: global softmax reduction
__global__ __launch_bounds__(256) void softmax_partial(
    const float* __restrict__ s, int E, float2* __restrict__ part) {
  __shared__ float mS[256], sS[256];
  int tid = threadIdx.x;
  float m = -1e30f, sum = 0.f;
  for (int i = blockIdx.x * 256 + tid; i < E; i += gridDim.x * 256) {
    float x = s[i];
    if (x > m) {
      sum = sum * __expf(m - x) + 1.f;
      m = x;
    } else {
      sum += __expf(x - m);
    }
  }
  mS[tid] = m;
  sS[tid] = sum;
  __syncthreads();
  for (int off = 128; off > 0; off >>= 1) {
    if (tid < off) {
      float m1 = mS[tid], s1 = sS[tid];
      float m2 = mS[tid + off], s2 = sS[tid + off];
      float M = fmaxf(m1, m2);
      mS[tid] = M;
      sS[tid] = s1 * __expf(m1 - M) + s2 * __expf(m2 - M);
    }
    __syncthreads();
  }
  if (tid == 0) part[blockIdx.x] = make_float2(mS[0], sS[0]);
}

__global__ __launch_bounds__(256) void softmax_final(
    const float2* __restrict__ part, int nPart, float* __restrict__ MS) {
  __shared__ float mS[256], sS[256];
  int tid = threadIdx.x;
  float m = -1e30f, sum = 0.f;
  for (int i = tid; i < nPart; i += 256) {
    float2 p = part[i];
    float M = fmaxf(m, p.x);
    sum = sum * __expf(m - M) + p.y * __expf(p.x - M);
    m = M;
  }
  mS[tid] = m;
  sS[tid] = sum;
  __syncthreads();
  for (int off = 128; off > 0; off >>= 1) {
    if (tid < off) {
      float m1 = mS[tid], s1 = sS[tid];
      float m2 = mS[tid + off], s2 = sS[tid + off];
      float M = fmaxf(m1, m2);
      mS[tid] = M;
      sS[tid] = s1 * __expf(m1 - M) + s2 * __expf(m2 - M);
    }
    __syncthreads();
  }
  if (tid == 0) {
    MS[0] = mS[0];
    MS[1] = 1.f / sS[0];
  }
}

// ---------------------------------------------------------------------------
// CSR build: deg histogram -> 3-step exclusive scan -> bucket fill
__global__ __launch_bounds__(256) void count_deg(const int* __restrict__ src,
                                                 int* __restrict__ deg, int E) {
  int e = blockIdx.x * 256 + threadIdx.x;
  if (e < E) atomicAdd(&deg[src[e]], 1);
}

__global__ __launch_bounds__(256) void scan1(const int* __restrict__ deg,
                                             int* __restrict__ incl,
                                             int* __restrict__ bsum, int N) {
  __shared__ int sh[256];
  int tid = threadIdx.x;
  int i = blockIdx.x * 256 + tid;
  sh[tid] = (i < N) ? deg[i] : 0;
  __syncthreads();
  for (int off = 1; off < 256; off <<= 1) {
    int tv = (tid >= off) ? sh[tid - off] : 0;
    __syncthreads();
    sh[tid] += tv;
    __syncthreads();
  }
  if (i < N) incl[i] = sh[tid];
  if (tid == 255) bsum[blockIdx.x] = sh[255];
}

__global__ __launch_bounds__(256) void scan2(int* __restrict__ bsum, int nb) {
  __shared__ int sh[256];
  int tid = threadIdx.x;
  sh[tid] = (tid < nb) ? bsum[tid] : 0;
  __syncthreads();
  for (int off = 1; off < 256; off <<= 1) {
    int tv = (tid >= off) ? sh[tid - off] : 0;
    __syncthreads();
    sh[tid] += tv;
    __syncthreads();
  }
  if (tid < nb) bsum[tid] = sh[tid];
}

__global__ __launch_bounds__(256) void scan3(const int* __restrict__ deg,
                                             const int* __restrict__ incl,
                                             const int* __restrict__ bsum,
                                             int* __restrict__ offs,
                                             int* __restrict__ cursor, int N,
                                             int E) {
  int i = blockIdx.x * 256 + threadIdx.x;
  if (i >= N) return;
  int base = (blockIdx.x > 0) ? bsum[blockIdx.x - 1] : 0;
  int ex = incl[i] - deg[i] + base;
  offs[i] = ex;
  cursor[i] = ex;
  if (i == N - 1) offs[N] = E;
}

// fill: cwt[j] = (tgt[e], s_raw[e]) bucketed by src[e]
__global__ __launch_bounds__(256) void fill_csr(
    const int* __restrict__ src, const int* __restrict__ tgt,
    const float* __restrict__ s, int* __restrict__ cursor,
    int2* __restrict__ cwt, int E) {
  int e = blockIdx.x * 256 + threadIdx.x;
  if (e >= E) return;
  int s_ = src[e];
  int j = atomicAdd(&cursor[s_], 1);
  cwt[j] = make_int2(tgt[e], __float_as_int(s[e]));
}

// ---------------------------------------------------------------------------
// K5: fused gather + softmax-normalize + layernorm.
// One wave per node (float2 per lane), 4 nodes per 256-block, x2 unroll.
__global__ __launch_bounds__(256) void gather_ln(
    const int* __restrict__ offs, const int2* __restrict__ cwt,
    const float* __restrict__ v, const float* __restrict__ MS,
    const float* __restrict__ gamma, const float* __restrict__ beta,
    float* __restrict__ y, int N) {
  int tid = threadIdx.x;
  int n = blockIdx.x * 4 + (tid >> 6);
  if (n >= N) return;  // wave-uniform
  int lane = tid & 63;
  float M = MS[0], inv = MS[1];
  int beg = offs[n], end = offs[n + 1];
  float a0 = 0.f, a1 = 0.f;
  int j = beg;
  for (; j + 1 < end; j += 2) {
    int2 p0 = cwt[j], p1 = cwt[j + 1];
    float w0 = __expf(__int_as_float(p0.y) - M) * inv;
    float w1 = __expf(__int_as_float(p1.y) - M) * inv;
    float2 v0 = *(const float2*)(v + (size_t)p0.x * 128 + lane * 2);
    float2 v1 = *(const float2*)(v + (size_t)p1.x * 128 + lane * 2);
    a0 += w0 * v0.x + w1 * v1.x;
    a1 += w0 * v0.y + w1 * v1.y;
  }
  if (j < end) {
    int2 p = cwt[j];
    float w = __expf(__int_as_float(p.y) - M) * inv;
    float2 vv = *(const float2*)(v + (size_t)p.x * 128 + lane * 2);
    a0 += w * vv.x;
    a1 += w * vv.y;
  }
  size_t base = (size_t)n * 128 + lane * 2;
  float2 hv = *(const float2*)(y + base);
  float y0 = hv.x + a0, y1 = hv.y + a1;
  float sum = y0 + y1, ssq = y0 * y0 + y1 * y1;
#pragma unroll
  for (int off = 1; off < 64; off <<= 1) {
    sum += __shfl_xor(sum, off);
    ssq += __shfl_xor(ssq, off);
  }
  float mu = sum * (1.f / 128.f);
  float var = ssq * (1.f / 128.f) - mu * mu;
  float rstd = rsqrtf(var + EPS);
  float2 g = *(const float2*)(gamma + lane * 2);
  float2 bt = *(const float2*)(beta + lane * 2);
  float2 out;
  out.x = g.x * (y0 - mu) * rstd + bt.x;
  out.y = g.y * (y1 - mu) * rstd + bt.y;
  *(float2*)(y + base) = out;
}

// ---------------------------------------------------------------------------
extern "C" void kernel_launch(void* const* d_in, const int* in_sizes, int n_in,
                              void* d_out, int out_size, void* d_ws,
                              size_t ws_size, hipStream_t stream) {
  const float* X  = (const float*)d_in[0];
  const float* EF = (const float*)d_in[1];
  const float* Wn = (const float*)d_in[2];
  const float* bn = (const float*)d_in[3];
  const float* Wq = (const float*)d_in[4];
  const float* bq = (const float*)d_in[5];
  const float* Wk = (const float*)d_in[6];
  const float* bk = (const float*)d_in[7];
  const float* Wv = (const float*)d_in[8];
  const float* bv = (const float*)d_in[9];
  const float* We = (const float*)d_in[10];
  const float* be = (const float*)d_in[11];
  const float* A1 = (const float*)d_in[12];
  const float* b1 = (const float*)d_in[13];
  const float* A2 = (const float*)d_in[14];
  const float* b2 = (const float*)d_in[15];
  const float* gamma = (const float*)d_in[16];
  const float* beta  = (const float*)d_in[17];
  const int* ei = (const int*)d_in[18];

  int N = in_sizes[0] / D;   // 50000
  int E = in_sizes[1] / DE;  // 400000
  const int* src = ei;
  const int* tgt = ei + E;

  float* h = (float*)d_out;  // h accumulated/normalized in place
  float* ws = (float*)d_ws;
  float* v     = ws;                                   // N*128 f32
  float* sbuf  = v + (size_t)N * D;                    // E f32
  float2* part = (float2*)(sbuf + E);                  // 1024
  float* MS    = (float*)(part + 1024);                // 4
  float* bfold = MS + 4;                               // 128
  unsigned short* Xb   = (unsigned short*)(bfold + 128);  // N*128
  unsigned short* q2p  = Xb + (size_t)N * D;              // N*128
  unsigned short* k2p  = q2p + (size_t)N * D;             // N*128
  unsigned short* AfqT = k2p + (size_t)N * D;             // 128*128
  unsigned short* AfkT = AfqT + 128 * 128;                // 128*128
  unsigned short* AfeT = AfkT + 128 * 128;                // 128*64
  unsigned short* WnT  = AfeT + 128 * 64;                 // 128*128
  unsigned short* WvT  = WnT + 128 * 128;                 // 128*128
  int* deg    = (int*)(WvT + 128 * 128);               // N
  int* incl   = deg + N;                               // N
  int* bsum   = incl + N;                              // 256
  int* cursor = bsum + 256;                            // N
  int* offs   = cursor + N;                            // N+2 (pad for align)
  int2* cwt   = (int2*)(offs + N + 2);                 // E

  int nbScan = (N + 255) / 256;  // 196 (<= 256)

  hipMemsetAsync(deg, 0, (size_t)N * sizeof(int), stream);
  fold_pack<<<577, 128, 0, stream>>>(Wq, Wk, We, A1, bq, bk, be, b1, Wn, Wv,
                                     AfqT, AfkT, AfeT, bfold, WnT, WvT);
  cvt_to_bf16<<<(N * D / 4 + 255) / 256, 256, 0, stream>>>(X, Xb, N * D / 4);
  count_deg<<<(E + 255) / 256, 256, 0, stream>>>(src, deg, E);
  scan1<<<nbScan, 256, 0, stream>>>(deg, incl, bsum, N);
  scan2<<<1, 256, 0, stream>>>(bsum, nbScan);
  scan3<<<nbScan, 256, 0, stream>>>(deg, incl, bsum, offs, cursor, N, E);
  node_gemm_mfma<<<dim3((N + 255) / 256, 4), 256, 0, stream>>>(
      Xb, WnT, WvT, AfqT, AfkT, bn, bv, h, v, q2p, k2p, N);
  edge_fused2<<<(E + 255) / 256, 256, 0, stream>>>(EF, AfeT, bfold, A2, b2,
                                                   q2p, k2p, src, tgt, sbuf, E);
  softmax_partial<<<1024, 256, 0, stream>>>(sbuf, E, part);
  softmax_final<<<1, 256, 0, stream>>>(part, 1024, MS);
  fill_csr<<<(E + 255) / 256, 256, 0, stream>>>(src, tgt, sbuf, cursor, cwt, E);
  gather_ln<<<(N + 3) / 4, 256, 0, stream>>>(offs, cwt, v, MS, gamma, beta, h,
                                             N);
}